// Round 8
// baseline (191.614 us; speedup 1.0000x reference)
//
#include <hip/hip_runtime.h>
#include <hip/hip_bf16.h>

typedef __hip_bfloat16 bf16;
typedef __attribute__((ext_vector_type(8))) short bf16x8;
typedef __attribute__((ext_vector_type(4))) float floatx4;

#define NB 16
#define NC 256
#define NPIX 4096
#define NHID 128
#define NH 4
#define ND 32
#define NMEM 4
#define QSCALE 0.17677669529663687f  // 32^-0.5

__device__ __forceinline__ void dma16(const void* g, void* l){
  __builtin_amdgcn_global_load_lds(
      (const __attribute__((address_space(1))) unsigned int*)g,
      (__attribute__((address_space(3))) unsigned int*)l, 16, 0, 0);
}

// ---------------- K0: zero atomic accumulators
__global__ void k0_zero(float* __restrict__ p, int n){
  int i = blockIdx.x*256 + threadIdx.x;
  if (i < n) p[i] = 0.f;
}

// ---------------- kW: pack wqkv*g -> bf16 in MFMA A-frag tile order.
// 16B chunk u: slice s=u/1536, tile=(u%1536)>>6, lane l=u&63;
// row = tile*16 + (l&15); k = s*32 + (l>>4)*8 + j (j=0..7).
__launch_bounds__(256)
__global__ void kW(const float* __restrict__ wqkv, const float* __restrict__ g,
                   bf16* __restrict__ wgpack){
  const int u = blockIdx.x*256 + threadIdx.x;     // 12288 chunks
  const int s = u / 1536;
  const int r = u - s*1536;
  const int tile = r >> 6, l = r & 63;
  const int row = tile*16 + (l & 15);
  const int kb  = s*32 + (l >> 4)*8;
  const float* wp = wqkv + (size_t)row*NC + kb;
  floatx4 w0 = *(const floatx4*)wp;
  floatx4 w1 = *(const floatx4*)(wp + 4);
  floatx4 g0 = *(const floatx4*)(g + kb);
  floatx4 g1 = *(const floatx4*)(g + kb + 4);
  alignas(16) bf16 tmp[8];
  #pragma unroll
  for (int i = 0; i < 4; ++i){
    tmp[i]   = __float2bfloat16(w0[i]*g0[i]);
    tmp[4+i] = __float2bfloat16(w1[i]*g1[i]);
  }
  *(uint4*)(wgpack + (size_t)u*8) = *(const uint4*)tmp;
}

// ---------------- kA: fused norm + qkv GEMM + q-softmax + P/ctx/z.
// x tile staged ONCE up front (full K in LDS bf16); K-loop is DMA(w)+MFMA only.
__launch_bounds__(256)
__global__ void kA(const float* __restrict__ x, const bf16* __restrict__ wgpack,
                   float* __restrict__ dout,
                   float* __restrict__ ctxu, float* __restrict__ zacc){
  __shared__ char smem alignas(16) [59648];
  bf16* Ab = (bf16*)smem;                         // 24 tiles x 1KB = 24576 (GEMM)
  bf16 (*Xb)[264] = (bf16(*)[264])(smem + 24576); // [64][264] = 33792 (GEMM)
  bf16 (*Pb)[72] = (bf16(*)[72])smem;             // [128][72] = 18432 (post, alias)
  bf16 (*Vb)[72] = (bf16(*)[72])(smem + 18432);   // [128][72] = 18432 (post, alias)
  float* ssqL = (float*)(smem + 58368);           // [256]
  float* sL   = (float*)(smem + 59392);           // [64]
  const int t = threadIdx.x;
  const int pb = blockIdx.x * 64, b = blockIdx.y;
  const int wv = t >> 6, lane = t & 63, m = lane & 15, q4 = lane >> 4;
  const int px_st = t & 63;
  const float* xb = x + (size_t)b*NC*NPIX;
  float ssq = 0.f;
  // ---- stage ALL of x^T (64 px x 256 ch) to LDS bf16; one barrier total
  #pragma unroll
  for (int batch = 0; batch < 4; ++batch){
    const int c0 = batch*64 + wv*16;
    const float* xp = xb + (size_t)c0*NPIX + pb + px_st;
    float v[16];
    #pragma unroll
    for (int j = 0; j < 16; ++j) v[j] = xp[(size_t)j*NPIX];
    alignas(16) bf16 tmp[16];
    #pragma unroll
    for (int j = 0; j < 16; ++j){ ssq += v[j]*v[j]; tmp[j] = __float2bfloat16(v[j]); }
    *(uint4*)&Xb[px_st][c0]     = *(const uint4*)&tmp[0];
    *(uint4*)&Xb[px_st][c0 + 8] = *(const uint4*)&tmp[8];
  }
  __syncthreads();
  // ---- K-loop: DMA w slice (L2-hot) + MFMA; no global-load latency inside
  floatx4 acc[6][4] = {};
  for (int s = 0; s < 8; ++s){
    {  // DMA w: wave wv loads its own 6 tiles (rows wv*96..+96)
      const bf16* gt = wgpack + ((size_t)(s*24 + wv*6)*64 + lane)*8;
      char* lt = smem + wv*6144;
      #pragma unroll
      for (int tt = 0; tt < 6; ++tt)
        dma16(gt + tt*512, lt + tt*1024);
    }
    __syncthreads();   // drain DMA
    bf16x8 bfr[4];
    #pragma unroll
    for (int pt = 0; pt < 4; ++pt)
      bfr[pt] = *(const bf16x8*)&Xb[pt*16 + m][s*32 + q4*8];
    #pragma unroll
    for (int rt = 0; rt < 6; ++rt){
      bf16x8 af = *(const bf16x8*)(Ab + (size_t)wv*3072 + rt*512 + (q4*16 + m)*8);
      #pragma unroll
      for (int pt = 0; pt < 4; ++pt)
        acc[rt][pt] = __builtin_amdgcn_mfma_f32_16x16x32_bf16(af, bfr[pt], acc[rt][pt], 0, 0, 0);
    }
    __syncthreads();   // protect Ab before next DMA
  }
  // finalize s (per px)
  ssqL[wv*64 + px_st] = ssq;
  __syncthreads();
  if (t < 64){
    float tot = ssqL[t] + ssqL[64 + t] + ssqL[128 + t] + ssqL[192 + t];
    sL[t] = 16.0f / fmaxf(sqrtf(tot), 1e-12f);
  }
  __syncthreads();   // sL ready; Ab/Xb reads done -> Pb/Vb writable
  float sv[4];
  #pragma unroll
  for (int pt = 0; pt < 4; ++pt) sv[pt] = sL[pt*16 + m];
  #pragma unroll
  for (int pr = 0; pr < 3; ++pr){
    const int ra = 2*pr, rb = 2*pr + 1;
    const int row0 = wv*96 + pr*32;
    const int type = row0 >> 7;          // 0=q, 1=k, 2=v
    if (type == 0){
      const int slice = row0 >> 5;       // head = q k-slice
      const int j0 = (q4 & 1)*4;
      #pragma unroll
      for (int pt = 0; pt < 4; ++pt){
        float va[4], vb[4];
        float mx = -1e30f;
        #pragma unroll
        for (int r = 0; r < 4; ++r){
          va[r] = acc[ra][pt][r]*sv[pt];
          vb[r] = acc[rb][pt][r]*sv[pt];
          mx = fmaxf(mx, fmaxf(va[r], vb[r]));
        }
        mx = fmaxf(mx, __shfl_xor(mx, 16, 64));
        mx = fmaxf(mx, __shfl_xor(mx, 32, 64));
        float se = 0.f;
        #pragma unroll
        for (int r = 0; r < 4; ++r){
          va[r] = __expf(va[r] - mx); vb[r] = __expf(vb[r] - mx);
          se += va[r] + vb[r];
        }
        se += __shfl_xor(se, 16, 64);
        se += __shfl_xor(se, 32, 64);
        const float inv = QSCALE / se;
        alignas(8) bf16 pka[4], pkb[4];
        #pragma unroll
        for (int r = 0; r < 4; ++r){
          pka[r] = __float2bfloat16(va[r]*inv);
          pkb[r] = __float2bfloat16(vb[r]*inv);
        }
        const int ca = (slice*4 + pt)*4 + (q4 >> 1);
        const int cb = ca + 2;
        bf16* pa = (bf16*)(dout + (size_t)(b*NC + ca)*NPIX + pb) + m*8 + j0;
        bf16* pv = (bf16*)(dout + (size_t)(b*NC + cb)*NPIX + pb) + m*8 + j0;
        *(uint2*)pa = *(const uint2*)pka;
        *(uint2*)pv = *(const uint2*)pkb;
      }
    } else if (type == 1){
      const int d0 = row0 - 128;
      float za[4] = {}, zb[4] = {};
      #pragma unroll
      for (int pt = 0; pt < 4; ++pt){
        #pragma unroll
        for (int r = 0; r < 4; ++r){
          float pa = __expf(acc[ra][pt][r]*sv[pt]);
          float pv = __expf(acc[rb][pt][r]*sv[pt]);
          za[r] += pa; zb[r] += pv;
          Pb[d0      + q4*4 + r][pt*16 + m] = __float2bfloat16(pa);
          Pb[d0 + 16 + q4*4 + r][pt*16 + m] = __float2bfloat16(pv);
        }
      }
      #pragma unroll
      for (int r = 0; r < 4; ++r){
        #pragma unroll
        for (int o = 1; o < 16; o <<= 1){
          za[r] += __shfl_xor(za[r], o, 64);
          zb[r] += __shfl_xor(zb[r], o, 64);
        }
      }
      if (m == 0){
        #pragma unroll
        for (int r = 0; r < 4; ++r){
          atomicAdd(&zacc[b*NHID + d0      + q4*4 + r], za[r]);
          atomicAdd(&zacc[b*NHID + d0 + 16 + q4*4 + r], zb[r]);
        }
      }
    } else {
      const int v0 = row0 - 256;
      #pragma unroll
      for (int pt = 0; pt < 4; ++pt)
        #pragma unroll
        for (int r = 0; r < 4; ++r){
          Vb[v0      + q4*4 + r][pt*16 + m] = __float2bfloat16(acc[ra][pt][r]*sv[pt]);
          Vb[v0 + 16 + q4*4 + r][pt*16 + m] = __float2bfloat16(acc[rb][pt][r]*sv[pt]);
        }
    }
  }
  __syncthreads();
  // ctx MFMA: wave wv = head wv; 64 toks in 2 K-steps
  floatx4 cx[2][2] = {};
  #pragma unroll
  for (int k0t = 0; k0t < 64; k0t += 32){
    bf16x8 af[2], bf[2];
    #pragma unroll
    for (int dt = 0; dt < 2; ++dt) af[dt] = *(const bf16x8*)&Pb[wv*32 + dt*16 + m][k0t + q4*8];
    #pragma unroll
    for (int et = 0; et < 2; ++et) bf[et] = *(const bf16x8*)&Vb[wv*32 + et*16 + m][k0t + q4*8];
    #pragma unroll
    for (int dt = 0; dt < 2; ++dt)
      #pragma unroll
      for (int et = 0; et < 2; ++et)
        cx[dt][et] = __builtin_amdgcn_mfma_f32_16x16x32_bf16(af[dt], bf[et], cx[dt][et], 0, 0, 0);
  }
  float* cb2 = ctxu + (size_t)(b*NH + wv)*ND*ND;
  #pragma unroll
  for (int dt = 0; dt < 2; ++dt)
    #pragma unroll
    for (int et = 0; et < 2; ++et)
      #pragma unroll
      for (int r = 0; r < 4; ++r)
        atomicAdd(&cb2[(dt*16 + q4*4 + r)*ND + et*16 + m], cx[dt][et][r]);
}

// ---------------- K4: Weff -> bf16, packed in MFMA A-frag tile order for k5.
__launch_bounds__(256)
__global__ void k4_weff(const float* __restrict__ ctxu, const float* __restrict__ zacc,
                        const float* __restrict__ memkv, const float* __restrict__ wout,
                        bf16* __restrict__ wpack){
  const int idx = blockIdx.x*256 + threadIdx.x;   // (b*256 + o)*128 + hd
  const int b   = idx >> 15;
  const int o   = (idx >> 7) & 255;
  const int hd  = idx & 127;
  const int h = hd >> 5, d = hd & 31;
  const float* mk = memkv + hd*NMEM;                       // mem_kv[0][h][d][j]
  float me[4];
  float z = zacc[b*NHID + hd];
  #pragma unroll
  for (int j = 0; j < 4; ++j){ me[j] = __expf(mk[j]); z += me[j]; }
  const float invz = 1.0f / z;
  const float* cp = ctxu + (size_t)((b*NH + h)*ND + d)*ND;
  const float* wp = wout + (size_t)o*NHID + h*ND;
  const float* mv = memkv + (size_t)(NHID + h*ND)*NMEM;    // mem_kv[1][h][e][j]
  float acc = 0.f;
  #pragma unroll
  for (int e = 0; e < ND; ++e){
    float ce = cp[e];
    #pragma unroll
    for (int j = 0; j < 4; ++j) ce += me[j]*mv[e*NMEM + j];
    acc += ce*wp[e];
  }
  const int slice = hd >> 5, q4k = (hd >> 3) & 3, j = hd & 7;
  const int tile = o >> 4, m16 = o & 15;
  wpack[((size_t)((b*4 + slice)*16 + tile)*64 + q4k*16 + m16)*8 + j] = __float2bfloat16(acc*invz);
}

// ---------------- K5: MFMA y = Weff @ q_s + bias -> RMSNorm -> dout rows 0..255.
// Both operands DMA-staged; stores vectorized via LDS transpose bounce.
__launch_bounds__(256)
__global__ void k5_out(float* dout, const bf16* __restrict__ wpack,
                       const float* __restrict__ bout, const float* __restrict__ gout){
  __shared__ char smem alignas(16) [21760];
  bf16* Wb = (bf16*)smem;                 // 16 tiles x 1KB = 16384
  bf16* Qb = (bf16*)(smem + 16384);       // 4 tiles x 1KB = 4096
  float* tb  = (float*)smem;              // [64][65] fp32 = 16640 (store phase, alias)
  float* red = (float*)(smem + 20480);    // [4][64]
  float* nf  = (float*)(smem + 21504);    // [64]
  const int t = threadIdx.x;
  const int pb = blockIdx.x * 64, b = blockIdx.y;
  const int wv = t >> 6, lane = t & 63, m = lane & 15, q4 = lane >> 4;
  floatx4 acc[4][4] = {};
  for (int s = 0; s < 4; ++s){
    __syncthreads();   // prev MFMA done
    {  // DMA Wb: wave wv loads its 4 tiles (rows wv*64..+64)
      const bf16* gt = wpack + ((size_t)((b*4 + s)*16 + wv*4)*64 + lane)*8;
      char* lt = smem + wv*4096;
      #pragma unroll
      for (int tt = 0; tt < 4; ++tt)
        dma16(gt + tt*512, lt + tt*1024);
    }
    {  // DMA Qb: wave wv loads px-tile wv; lane l -> row c'=(s*4+wv)*4+(l>>4)
      const char* gq = (const char*)(dout + (size_t)(b*NC + (s*4 + wv)*4 + q4)*NPIX + pb) + m*16;
      dma16(gq, smem + 16384 + wv*1024);
    }
    __syncthreads();   // vmcnt drain
    bf16x8 bfr[4];
    #pragma unroll
    for (int pt = 0; pt < 4; ++pt)
      bfr[pt] = *(const bf16x8*)(Qb + pt*512 + (q4*16 + m)*8);
    #pragma unroll
    for (int rt = 0; rt < 4; ++rt){
      bf16x8 af = *(const bf16x8*)(Wb + (size_t)(wv*4 + rt)*512 + (q4*16 + m)*8);
      #pragma unroll
      for (int pt = 0; pt < 4; ++pt)
        acc[rt][pt] = __builtin_amdgcn_mfma_f32_16x16x32_bf16(af, bfr[pt], acc[rt][pt], 0, 0, 0);
    }
  }
  // bias + ssq partials
  float ps[4] = {0.f, 0.f, 0.f, 0.f};
  #pragma unroll
  for (int rt = 0; rt < 4; ++rt){
    const int row = wv*64 + rt*16 + q4*4;
    #pragma unroll
    for (int r = 0; r < 4; ++r){
      const float bias = bout[row + r];
      #pragma unroll
      for (int pt = 0; pt < 4; ++pt){
        acc[rt][pt][r] += bias;
        ps[pt] += acc[rt][pt][r]*acc[rt][pt][r];
      }
    }
  }
  #pragma unroll
  for (int pt = 0; pt < 4; ++pt){
    ps[pt] += __shfl_xor(ps[pt], 16, 64);
    ps[pt] += __shfl_xor(ps[pt], 32, 64);
  }
  __syncthreads();   // MFMA reads done; reuse smem
  if (q4 == 0){
    #pragma unroll
    for (int pt = 0; pt < 4; ++pt) red[wv*64 + pt*16 + m] = ps[pt];
  }
  __syncthreads();
  if (t < 64){
    float tot = red[t] + red[64 + t] + red[128 + t] + red[192 + t];
    nf[t] = 16.0f / fmaxf(sqrtf(tot), 1e-12f);
  }
  __syncthreads();
  float nv[4];
  #pragma unroll
  for (int pt = 0; pt < 4; ++pt) nv[pt] = nf[pt*16 + m];
  // ---- store phase: per rt, transpose 64x64 tile through LDS, float4 stores
  for (int rt = 0; rt < 4; ++rt){
    __syncthreads();   // previous copy-out readers done (iter0: nf phase done)
    #pragma unroll
    for (int r = 0; r < 4; ++r){
      const int row = wv*64 + rt*16 + q4*4 + r;
      const float gg = gout[row];
      #pragma unroll
      for (int pt = 0; pt < 4; ++pt)
        tb[(wv*16 + q4*4 + r)*65 + pt*16 + m] = acc[rt][pt][r]*nv[pt]*gg;
    }
    __syncthreads();
    #pragma unroll
    for (int i = 0; i < 4; ++i){
      const int idx = i*256 + t;          // 0..1023 float4 slots
      const int rowslot = idx >> 4;       // wv2*16 + rr
      const int px4 = idx & 15;
      const int wv2 = rowslot >> 4, rr = rowslot & 15;
      const int row = wv2*64 + rt*16 + rr;
      *(floatx4*)(dout + (size_t)(b*NC + row)*NPIX + pb + px4*4) =
          *(const floatx4*)&tb[rowslot*65 + px4*4];
    }
  }
}

extern "C" void kernel_launch(void* const* d_in, const int* in_sizes, int n_in,
                              void* d_out, int out_size, void* d_ws, size_t ws_size,
                              hipStream_t stream) {
  (void)in_sizes; (void)n_in; (void)out_size; (void)ws_size;
  const float* x     = (const float*)d_in[0];
  const float* ng    = (const float*)d_in[1];
  const float* wqkv  = (const float*)d_in[2];
  const float* memkv = (const float*)d_in[3];
  const float* wout  = (const float*)d_in[4];
  const float* bout  = (const float*)d_in[5];
  const float* gout  = (const float*)d_in[6];
  float* dout = (float*)d_out;
  char* ws = (char*)d_ws;
  // workspace layout — total 1,515,520 B (~1.45 MB)
  bf16*  wgpack = (bf16*)(ws);              // 8*24*64*8*2  = 196608
  bf16*  wpack  = (bf16*)(ws + 196608);     // 16*4*16*64*8*2 = 1048576
  float* ctxu   = (float*)(ws + 1245184);   // 16*4*32*32*4 = 262144
  float* zacc   = (float*)(ws + 1507328);   // 16*128*4     = 8192

  k0_zero<<<dim3(264),     256, 0, stream>>>(ctxu, 65536 + 2048);
  kW     <<<dim3(48),      256, 0, stream>>>(wqkv, ng, wgpack);
  kA     <<<dim3(64, 16),  256, 0, stream>>>(x, wgpack, dout, ctxu, zacc);
  k4_weff<<<dim3(2048),    256, 0, stream>>>(ctxu, zacc, memkv, wout, wpack);
  k5_out <<<dim3(64, 16),  256, 0, stream>>>(dout, wpack, bout, gout);
}